// Round 1
// 242.733 us; speedup vs baseline: 1.1306x; 1.1306x over previous
//
#include <hip/hip_runtime.h>

#define NUSERS 100000
#define NITEMS 50000
#define NNODES 150000
#define DIM 64
#define E0 600000
#define E2 (2 * E0)
#define BB 8192
#define LW 1e-4f
#define NN16 150016
#define LOSS_BLOCKS 128
#define UBLK 6250   // cdiv(NUSERS, 16)  (16 nodes per 512-thr block)
#define IBLK 3125   // cdiv(NITEMS, 16)

// ---- counting-sort CSR build (no device-scope atomics) ----
#define NBUCK 1172      // ceil(NNODES / 128): bucket = node >> 7
#define CHUNK_E 2048    // edges per chunk
#define CHUNKS 293      // ceil(E0 / CHUNK_E); NBUCK == 4*CHUNKS (grid reuse)
#define CPAD 320        // padded chunk stride in cnt matrix (bucket-major)
#define BCAP 3072       // LDS staging cap per bucket (max observed ~1.7K)

// ---- bf16 helpers (fp32 <-> packed bf16 pair in a uint) ----
__device__ __forceinline__ float bf_lo(unsigned u) { return __uint_as_float(u << 16); }
__device__ __forceinline__ float bf_hi(unsigned u) { return __uint_as_float(u & 0xffff0000u); }
__device__ __forceinline__ unsigned rne16(float x) {
  unsigned u = __float_as_uint(x);
  return (u + 0x7fffu + ((u >> 16) & 1u)) >> 16;
}
__device__ __forceinline__ unsigned pack2(float lo, float hi) {
  return rne16(lo) | (rne16(hi) << 16);
}

// Pass 1: per-chunk LDS histogram of bucket counts.
// cnt is bucket-major: cnt[b*CPAD + c] so the per-bucket scan is coalesced.
__global__ __launch_bounds__(256) void k_bcount(const int* __restrict__ eu,
                                                const int* __restrict__ ei,
                                                int* __restrict__ cnt) {
  __shared__ int h[NBUCK];
  for (int i = threadIdx.x; i < NBUCK; i += 256) h[i] = 0;
  __syncthreads();
  int c = blockIdx.x;
  int e0 = c * CHUNK_E;
  int e1 = min(e0 + CHUNK_E, E0);
  for (int e = e0 + threadIdx.x; e < e1; e += 256) {
    int u = eu[e];
    int it = NUSERS + ei[e];
    atomicAdd(&h[u >> 7], 1);
    atomicAdd(&h[it >> 7], 1);
  }
  __syncthreads();
  for (int i = threadIdx.x; i < NBUCK; i += 256) cnt[(size_t)i * CPAD + c] = h[i];
}

// Pass 2a: per-bucket exclusive scan over chunks (wave per bucket, in place)
// + bucket totals. Lane loads are coalesced (bucket-major layout).
__global__ __launch_bounds__(256) void k_bscan1(int* __restrict__ cnt,
                                                int* __restrict__ btot) {
  int b = blockIdx.x * 4 + (threadIdx.x >> 6);   // grid = NBUCK/4 blocks
  int lane = threadIdx.x & 63;
  int* row = cnt + (size_t)b * CPAD;
  int carry = 0;
  for (int c0 = 0; c0 < CHUNKS; c0 += 64) {
    int c = c0 + lane;
    int v = (c < CHUNKS) ? row[c] : 0;
    int s = v;
    #pragma unroll
    for (int m = 1; m < 64; m <<= 1) {
      int t = __shfl_up(s, m);
      if (lane >= m) s += t;
    }
    if (c < CHUNKS) row[c] = carry + s - v;      // exclusive within bucket
    carry += __shfl(s, 63);
  }
  if (lane == 63) btot[b] = carry;
}

// Pass 2b: exclusive scan of bucket totals -> bbase (CSR region starts).
__global__ void k_bbase(const int* __restrict__ btot, int* __restrict__ bbase) {
  __shared__ int s[1024];
  int t = threadIdx.x;
  int i0 = 2 * t, i1 = 2 * t + 1;
  int v0 = (i0 < NBUCK) ? btot[i0] : 0;
  int v1 = (i1 < NBUCK) ? btot[i1] : 0;
  s[t] = v0 + v1;
  __syncthreads();
  for (int off = 1; off < 1024; off <<= 1) {
    int x = 0;
    if (t >= off) x = s[t - off];
    __syncthreads();
    if (t >= off) s[t] += x;
    __syncthreads();
  }
  int base = (t > 0) ? s[t - 1] : 0;
  if (i0 < NBUCK) bbase[i0] = base;
  if (i1 < NBUCK) bbase[i1] = base + v0;
}

// Pass 3: scatter directed edges into bucket regions. Each chunk owns a
// disjoint window per bucket (from the matrix scan) -> LDS atomics only.
// Payload: (neighbor_id << 7) | (dst & 127); neighbor < 150016 < 2^18.
__global__ __launch_bounds__(256) void k_bscatter(const int* __restrict__ eu,
                                                  const int* __restrict__ ei,
                                                  const int* __restrict__ cnt,
                                                  const int* __restrict__ bbase,
                                                  unsigned* __restrict__ pk) {
  __shared__ int soff[NBUCK];
  int c = blockIdx.x;
  for (int i = threadIdx.x; i < NBUCK; i += 256)
    soff[i] = cnt[(size_t)i * CPAD + c] + bbase[i];
  __syncthreads();
  int e0 = c * CHUNK_E;
  int e1 = min(e0 + CHUNK_E, E0);
  for (int e = e0 + threadIdx.x; e < e1; e += 256) {
    int u = eu[e];
    int it = NUSERS + ei[e];
    int s1 = atomicAdd(&soff[u >> 7], 1);
    pk[s1] = ((unsigned)it << 7) | (unsigned)(u & 127);
    int s2 = atomicAdd(&soff[it >> 7], 1);
    pk[s2] = ((unsigned)u << 7) | (unsigned)(it & 127);
  }
}

// Pass 4: one block per bucket (128 nodes). LDS histogram -> deg/ptr/dinv,
// LDS rank -> final col. Fused scaled-cast s0 = dinv * G (bf16) since dinv
// is produced here (replaces the old k_place_cast cast half).
__global__ __launch_bounds__(256) void k_bucket_csr(
    const unsigned* __restrict__ pk, const int* __restrict__ btot,
    const int* __restrict__ bbase, int* __restrict__ deg, int* __restrict__ ptr,
    float* __restrict__ dinv, int* __restrict__ col,
    const float4* __restrict__ Gu4, const float4* __restrict__ Gi4,
    uint2* __restrict__ h0) {
  __shared__ unsigned sitm[BCAP];
  __shared__ int ldeg[128], lscan[128], lcnt[128];
  __shared__ float sdv[128];
  int b = blockIdx.x;
  int base = bbase[b];
  int n = btot[b];
  for (int i = threadIdx.x; i < n; i += 256)
    if (i < BCAP) sitm[i] = pk[base + i];
  if (threadIdx.x < 128) { ldeg[threadIdx.x] = 0; lcnt[threadIdx.x] = 0; }
  __syncthreads();
  for (int i = threadIdx.x; i < n; i += 256) {
    unsigned p = (i < BCAP) ? sitm[i] : pk[base + i];
    atomicAdd(&ldeg[p & 127], 1);
  }
  __syncthreads();
  if (threadIdx.x < 128) lscan[threadIdx.x] = ldeg[threadIdx.x];
  __syncthreads();
  for (int off = 1; off < 128; off <<= 1) {
    int t = 0;
    if (threadIdx.x < 128 && (int)threadIdx.x >= off) t = lscan[threadIdx.x - off];
    __syncthreads();
    if (threadIdx.x < 128 && (int)threadIdx.x >= off) lscan[threadIdx.x] += t;
    __syncthreads();
  }
  int node = b * 128 + threadIdx.x;
  if (threadIdx.x < 128) {
    int d = ldeg[threadIdx.x];
    lscan[threadIdx.x] -= d;               // -> exclusive (bucket-local)
    float dv = d > 0 ? rsqrtf((float)d) : 0.0f;
    sdv[threadIdx.x] = dv;
    if (node < NNODES) {
      deg[node] = d;
      ptr[node] = base + lscan[threadIdx.x];
      dinv[node] = dv;
    }
  }
  __syncthreads();
  for (int i = threadIdx.x; i < n; i += 256) {
    unsigned p = (i < BCAP) ? sitm[i] : pk[base + i];
    int dl = p & 127;
    int pos = base + lscan[dl] + atomicAdd(&lcnt[dl], 1);
    col[pos] = (int)(p >> 7);
  }
  // scaled cast: h0 = bf16(dinv * G) for this bucket's 128 nodes
  for (int w = threadIdx.x; w < 128 * 16; w += 256) {
    int nl = w >> 4, q = w & 15;
    int nd = b * 128 + nl;
    if (nd < NNODES) {
      float dv = sdv[nl];
      float4 v = (nd < NUSERS) ? Gu4[(size_t)nd * 16 + q]
                               : Gi4[(size_t)(nd - NUSERS) * 16 + q];
      h0[(size_t)nd * 16 + q] =
          make_uint2(pack2(dv * v.x, dv * v.y), pack2(dv * v.z, dv * v.w));
    }
  }
}

// Scaled-space SpMM: s_out(n) = dinv(n)^2 * sum_{c in N(n)} s_in(c).
// No per-neighbor weights (deleted dinv[c] gather). 2 nodes per wave for MLP.
// lane = 8*sub + q: sub walks neighbors stride-8, q covers row in uint4 chunks.
__global__ __launch_bounds__(512) void k_spmm2(
    const int* __restrict__ ptr, const int* __restrict__ deg,
    const int* __restrict__ col, const float* __restrict__ dinv,
    const uint4* __restrict__ h, uint4* __restrict__ hout) {
  int wid = threadIdx.x >> 6;
  int lane = threadIdx.x & 63;
  int sub = lane >> 3;
  int q = lane & 7;
  int gA, coff;
  const uint4* hsrc;
  if (blockIdx.x < UBLK) {           // user destinations gather from item half
    gA = blockIdx.x * 16 + wid * 2;
    coff = NUSERS;
    hsrc = h + (size_t)NUSERS * 8;
  } else {                            // item destinations gather from user half
    gA = NUSERS + (blockIdx.x - UBLK) * 16 + wid * 2;
    coff = 0;
    hsrc = h;
  }
  int gB = gA + 1;
  int stA = ptr[gA], dgA = deg[gA];
  int stB = ptr[gB], dgB = deg[gB];
  float dnA = dinv[gA], dnB = dinv[gB];
  int cA = (sub < dgA) ? col[stA + sub] : -1;
  int cB = (sub < dgB) ? col[stB + sub] : -1;
  uint4 xA = {0, 0, 0, 0}, xB = {0, 0, 0, 0};
  if (cA >= 0) xA = hsrc[(size_t)(cA - coff) * 8 + q];
  if (cB >= 0) xB = hsrc[(size_t)(cB - coff) * 8 + q];
  float aA0 = bf_lo(xA.x), aA1 = bf_hi(xA.x), aA2 = bf_lo(xA.y), aA3 = bf_hi(xA.y);
  float aA4 = bf_lo(xA.z), aA5 = bf_hi(xA.z), aA6 = bf_lo(xA.w), aA7 = bf_hi(xA.w);
  float aB0 = bf_lo(xB.x), aB1 = bf_hi(xB.x), aB2 = bf_lo(xB.y), aB3 = bf_hi(xB.y);
  float aB4 = bf_lo(xB.z), aB5 = bf_hi(xB.z), aB6 = bf_lo(xB.w), aB7 = bf_hi(xB.w);
  for (int j = stA + 8 + sub; j < stA + dgA; j += 8) {
    int c = col[j];
    uint4 x = hsrc[(size_t)(c - coff) * 8 + q];
    aA0 += bf_lo(x.x); aA1 += bf_hi(x.x); aA2 += bf_lo(x.y); aA3 += bf_hi(x.y);
    aA4 += bf_lo(x.z); aA5 += bf_hi(x.z); aA6 += bf_lo(x.w); aA7 += bf_hi(x.w);
  }
  for (int j = stB + 8 + sub; j < stB + dgB; j += 8) {
    int c = col[j];
    uint4 x = hsrc[(size_t)(c - coff) * 8 + q];
    aB0 += bf_lo(x.x); aB1 += bf_hi(x.x); aB2 += bf_lo(x.y); aB3 += bf_hi(x.y);
    aB4 += bf_lo(x.z); aB5 += bf_hi(x.z); aB6 += bf_lo(x.w); aB7 += bf_hi(x.w);
  }
  #pragma unroll
  for (int m = 8; m <= 32; m <<= 1) {
    aA0 += __shfl_xor(aA0, m); aA1 += __shfl_xor(aA1, m);
    aA2 += __shfl_xor(aA2, m); aA3 += __shfl_xor(aA3, m);
    aA4 += __shfl_xor(aA4, m); aA5 += __shfl_xor(aA5, m);
    aA6 += __shfl_xor(aA6, m); aA7 += __shfl_xor(aA7, m);
    aB0 += __shfl_xor(aB0, m); aB1 += __shfl_xor(aB1, m);
    aB2 += __shfl_xor(aB2, m); aB3 += __shfl_xor(aB3, m);
    aB4 += __shfl_xor(aB4, m); aB5 += __shfl_xor(aB5, m);
    aB6 += __shfl_xor(aB6, m); aB7 += __shfl_xor(aB7, m);
  }
  if (sub == 0) {
    float sA = dnA * dnA;
    float sB = dnB * dnB;
    hout[(size_t)gA * 8 + q] = make_uint4(pack2(aA0 * sA, aA1 * sA), pack2(aA2 * sA, aA3 * sA),
                                          pack2(aA4 * sA, aA5 * sA), pack2(aA6 * sA, aA7 * sA));
    hout[(size_t)gB * 8 + q] = make_uint4(pack2(aB0 * sB, aB1 * sB), pack2(aB2 * sB, aB3 * sB),
                                          pack2(aB4 * sB, aB5 * sB), pack2(aB6 * sB, aB7 * sB));
  }
}

__device__ __forceinline__ int decode_node(int k, const int* __restrict__ usr,
                                           const int* __restrict__ pos,
                                           const int* __restrict__ neg, int* coff) {
  if (k < BB) { *coff = NUSERS; return usr[k]; }
  if (k < 2 * BB) { *coff = 0; return NUSERS + pos[k - BB]; }
  *coff = 0; return NUSERS + neg[k - 2 * BB];
}

// Layer-3 SpMM only at the <=3*BB batch nodes (duplicates write identical
// values — benign). Same 2-nodes-per-wave structure.
__global__ __launch_bounds__(512) void k_spmm_batch(
    const int* __restrict__ usr, const int* __restrict__ pos, const int* __restrict__ neg,
    const int* __restrict__ ptr, const int* __restrict__ deg,
    const int* __restrict__ col, const float* __restrict__ dinv,
    const uint4* __restrict__ h, uint4* __restrict__ hout) {
  int wid = threadIdx.x >> 6;
  int lane = threadIdx.x & 63;
  int sub = lane >> 3;
  int q = lane & 7;
  int k0 = blockIdx.x * 16 + wid * 2;
  int cofA, cofB;
  int gA = decode_node(k0, usr, pos, neg, &cofA);
  int gB = decode_node(k0 + 1, usr, pos, neg, &cofB);
  const uint4* hsA = h + (size_t)cofA * 8;
  const uint4* hsB = h + (size_t)cofB * 8;
  int stA = ptr[gA], dgA = deg[gA];
  int stB = ptr[gB], dgB = deg[gB];
  float dnA = dinv[gA], dnB = dinv[gB];
  int cA = (sub < dgA) ? col[stA + sub] : -1;
  int cB = (sub < dgB) ? col[stB + sub] : -1;
  uint4 xA = {0, 0, 0, 0}, xB = {0, 0, 0, 0};
  if (cA >= 0) xA = hsA[(size_t)(cA - cofA) * 8 + q];
  if (cB >= 0) xB = hsB[(size_t)(cB - cofB) * 8 + q];
  float aA0 = bf_lo(xA.x), aA1 = bf_hi(xA.x), aA2 = bf_lo(xA.y), aA3 = bf_hi(xA.y);
  float aA4 = bf_lo(xA.z), aA5 = bf_hi(xA.z), aA6 = bf_lo(xA.w), aA7 = bf_hi(xA.w);
  float aB0 = bf_lo(xB.x), aB1 = bf_hi(xB.x), aB2 = bf_lo(xB.y), aB3 = bf_hi(xB.y);
  float aB4 = bf_lo(xB.z), aB5 = bf_hi(xB.z), aB6 = bf_lo(xB.w), aB7 = bf_hi(xB.w);
  for (int j = stA + 8 + sub; j < stA + dgA; j += 8) {
    int c = col[j];
    uint4 x = hsA[(size_t)(c - cofA) * 8 + q];
    aA0 += bf_lo(x.x); aA1 += bf_hi(x.x); aA2 += bf_lo(x.y); aA3 += bf_hi(x.y);
    aA4 += bf_lo(x.z); aA5 += bf_hi(x.z); aA6 += bf_lo(x.w); aA7 += bf_hi(x.w);
  }
  for (int j = stB + 8 + sub; j < stB + dgB; j += 8) {
    int c = col[j];
    uint4 x = hsB[(size_t)(c - cofB) * 8 + q];
    aB0 += bf_lo(x.x); aB1 += bf_hi(x.x); aB2 += bf_lo(x.y); aB3 += bf_hi(x.y);
    aB4 += bf_lo(x.z); aB5 += bf_hi(x.z); aB6 += bf_lo(x.w); aB7 += bf_hi(x.w);
  }
  #pragma unroll
  for (int m = 8; m <= 32; m <<= 1) {
    aA0 += __shfl_xor(aA0, m); aA1 += __shfl_xor(aA1, m);
    aA2 += __shfl_xor(aA2, m); aA3 += __shfl_xor(aA3, m);
    aA4 += __shfl_xor(aA4, m); aA5 += __shfl_xor(aA5, m);
    aA6 += __shfl_xor(aA6, m); aA7 += __shfl_xor(aA7, m);
    aB0 += __shfl_xor(aB0, m); aB1 += __shfl_xor(aB1, m);
    aB2 += __shfl_xor(aB2, m); aB3 += __shfl_xor(aB3, m);
    aB4 += __shfl_xor(aB4, m); aB5 += __shfl_xor(aB5, m);
    aB6 += __shfl_xor(aB6, m); aB7 += __shfl_xor(aB7, m);
  }
  if (sub == 0) {
    float sA = dnA * dnA;
    float sB = dnB * dnB;
    hout[(size_t)gA * 8 + q] = make_uint4(pack2(aA0 * sA, aA1 * sA), pack2(aA2 * sA, aA3 * sA),
                                          pack2(aA4 * sA, aA5 * sA), pack2(aA6 * sA, aA7 * sA));
    hout[(size_t)gB * 8 + q] = make_uint4(pack2(aB0 * sB, aB1 * sB), pack2(aB2 * sB, aB3 * sB),
                                          pack2(aB4 * sB, aB5 * sB), pack2(aB6 * sB, aB7 * sB));
  }
}

// Fused batch gather + layer sum + BPR loss; h_l = sqrt(deg)*s_l.
__global__ void k_loss(const int* __restrict__ usr, const int* __restrict__ pos,
                       const int* __restrict__ neg, const int* __restrict__ deg,
                       const float4* __restrict__ Gu4, const float4* __restrict__ Gi4,
                       const uint2* __restrict__ h1, const uint2* __restrict__ h2,
                       const uint2* __restrict__ h3, float* __restrict__ bpart) {
  __shared__ float sL[4], sR[4];
  int wid = threadIdx.x >> 6;
  int lane = threadIdx.x & 63;
  int r = lane >> 4;
  int q = lane & 15;
  int gw = blockIdx.x * 4 + wid;
  int nw = gridDim.x * 4;
  const float s = 0.25f;
  float accL = 0.0f, accR = 0.0f;
  for (int b4 = gw; b4 < BB / 4; b4 += nw) {
    int b = b4 * 4 + r;
    int iu = usr[b], ip = pos[b], ig = neg[b];
    float sdu = sqrtf((float)deg[iu]);
    float sdp = sqrtf((float)deg[NUSERS + ip]);
    float sdn = sqrtf((float)deg[NUSERS + ig]);
    size_t ou = (size_t)iu * 16 + q;
    size_t op = ((size_t)NUSERS + ip) * 16 + q;
    size_t on = ((size_t)NUSERS + ig) * 16 + q;
    float4 u = Gu4[ou];
    float4 p = Gi4[(size_t)ip * 16 + q];
    float4 g = Gi4[(size_t)ig * 16 + q];
    float4 su = {0, 0, 0, 0}, sp = {0, 0, 0, 0}, sg = {0, 0, 0, 0};
    uint2 v;
    v = h1[ou]; su.x += bf_lo(v.x); su.y += bf_hi(v.x); su.z += bf_lo(v.y); su.w += bf_hi(v.y);
    v = h2[ou]; su.x += bf_lo(v.x); su.y += bf_hi(v.x); su.z += bf_lo(v.y); su.w += bf_hi(v.y);
    v = h3[ou]; su.x += bf_lo(v.x); su.y += bf_hi(v.x); su.z += bf_lo(v.y); su.w += bf_hi(v.y);
    v = h1[op]; sp.x += bf_lo(v.x); sp.y += bf_hi(v.x); sp.z += bf_lo(v.y); sp.w += bf_hi(v.y);
    v = h2[op]; sp.x += bf_lo(v.x); sp.y += bf_hi(v.x); sp.z += bf_lo(v.y); sp.w += bf_hi(v.y);
    v = h3[op]; sp.x += bf_lo(v.x); sp.y += bf_hi(v.x); sp.z += bf_lo(v.y); sp.w += bf_hi(v.y);
    v = h1[on]; sg.x += bf_lo(v.x); sg.y += bf_hi(v.x); sg.z += bf_lo(v.y); sg.w += bf_hi(v.y);
    v = h2[on]; sg.x += bf_lo(v.x); sg.y += bf_hi(v.x); sg.z += bf_lo(v.y); sg.w += bf_hi(v.y);
    v = h3[on]; sg.x += bf_lo(v.x); sg.y += bf_hi(v.x); sg.z += bf_lo(v.y); sg.w += bf_hi(v.y);
    u.x = (u.x + sdu * su.x) * s; u.y = (u.y + sdu * su.y) * s;
    u.z = (u.z + sdu * su.z) * s; u.w = (u.w + sdu * su.w) * s;
    p.x = (p.x + sdp * sp.x) * s; p.y = (p.y + sdp * sp.y) * s;
    p.z = (p.z + sdp * sp.z) * s; p.w = (p.w + sdp * sp.w) * s;
    g.x = (g.x + sdn * sg.x) * s; g.y = (g.y + sdn * sg.y) * s;
    g.z = (g.z + sdn * sg.z) * s; g.w = (g.w + sdn * sg.w) * s;
    float dp = u.x * p.x + u.y * p.y + u.z * p.z + u.w * p.w;
    float dn = u.x * g.x + u.y * g.y + u.z * g.z + u.w * g.w;
    float rg = u.x * u.x + u.y * u.y + u.z * u.z + u.w * u.w
             + p.x * p.x + p.y * p.y + p.z * p.z + p.w * p.w
             + g.x * g.x + g.y * g.y + g.z * g.z + g.w * g.w;
    #pragma unroll
    for (int m = 1; m <= 8; m <<= 1) {
      dp += __shfl_xor(dp, m);
      dn += __shfl_xor(dn, m);
      rg += __shfl_xor(rg, m);
    }
    if (q == 0) {
      float diff = dp - dn;
      accL -= fminf(diff, 0.0f) - log1pf(expf(-fabsf(diff)));
      accR += rg;
    }
  }
  accL += __shfl_xor(accL, 16); accR += __shfl_xor(accR, 16);
  accL += __shfl_xor(accL, 32); accR += __shfl_xor(accR, 32);
  if (lane == 0) { sL[wid] = accL; sR[wid] = accR; }
  __syncthreads();
  if (threadIdx.x == 0) {
    bpart[blockIdx.x] = sL[0] + sL[1] + sL[2] + sL[3];
    bpart[LOSS_BLOCKS + blockIdx.x] = sR[0] + sR[1] + sR[2] + sR[3];
  }
}

__global__ void k_final(const float* __restrict__ bpart, float* __restrict__ out) {
  int lane = threadIdx.x;
  float l = bpart[lane] + bpart[lane + 64];
  float r = bpart[LOSS_BLOCKS + lane] + bpart[LOSS_BLOCKS + lane + 64];
  for (int off = 32; off > 0; off >>= 1) {
    l += __shfl_down(l, off);
    r += __shfl_down(r, off);
  }
  if (lane == 0) out[0] = l * (1.0f / BB) + LW * 0.5f * r * (1.0f / BB);
}

extern "C" void kernel_launch(void* const* d_in, const int* in_sizes, int n_in,
                              void* d_out, int out_size, void* d_ws, size_t ws_size,
                              hipStream_t stream) {
  const float* Gu = (const float*)d_in[0];
  const float* Gi = (const float*)d_in[1];
  const int* eu  = (const int*)d_in[2];
  const int* ei  = (const int*)d_in[3];
  const int* usr = (const int*)d_in[4];
  const int* pos = (const int*)d_in[5];
  const int* neg = (const int*)d_in[6];
  float* out = (float*)d_out;

  // Workspace: deg/ptr/dinv (1.8 MB) + col (9.6 MB) + h0..h3 (76.8 MB).
  // Build-phase scratch aliases not-yet-live h buffers:
  //   pk (9.6 MB) -> h1, cnt matrix (1.5 MB) -> h2, btot/bbase -> h3.
  int* deg    = (int*)d_ws;                  // NN16
  int* ptr    = deg + NN16;                  // NN16
  float* dinv = (float*)(ptr + NN16);        // NN16
  int* col    = (int*)(dinv + NN16);         // E2
  uint2* h0   = (uint2*)(col + E2);          // NNODES*16 uint2 each (19.2 MB)
  uint2* h1   = h0 + (size_t)NNODES * 16;
  uint2* h2   = h1 + (size_t)NNODES * 16;
  uint2* h3   = h2 + (size_t)NNODES * 16;
  float* bpart = (float*)(h3 + (size_t)NNODES * 16);  // 2*LOSS_BLOCKS

  unsigned* pk = (unsigned*)h1;              // E2 (scattered directed edges)
  int* cnt     = (int*)h2;                   // NBUCK * CPAD
  int* btot    = (int*)h3;                   // NBUCK
  int* bbase   = btot + 1280;                // NBUCK

  const float4* Gu4 = (const float4*)Gu;
  const float4* Gi4 = (const float4*)Gi;

  // CSR build via two-level counting sort — zero device-scope atomics.
  k_bcount<<<CHUNKS, 256, 0, stream>>>(eu, ei, cnt);
  k_bscan1<<<NBUCK / 4, 256, 0, stream>>>(cnt, btot);
  k_bbase<<<1, 1024, 0, stream>>>(btot, bbase);
  k_bscatter<<<CHUNKS, 256, 0, stream>>>(eu, ei, cnt, bbase, pk);
  k_bucket_csr<<<NBUCK, 256, 0, stream>>>(pk, btot, bbase, deg, ptr, dinv, col,
                                          Gu4, Gi4, h0);

  k_spmm2<<<UBLK + IBLK, 512, 0, stream>>>(ptr, deg, col, dinv,
                                           (const uint4*)h0, (uint4*)h1);
  k_spmm2<<<UBLK + IBLK, 512, 0, stream>>>(ptr, deg, col, dinv,
                                           (const uint4*)h1, (uint4*)h2);
  k_spmm_batch<<<(3 * BB) / 16, 512, 0, stream>>>(usr, pos, neg, ptr, deg, col, dinv,
                                                  (const uint4*)h2, (uint4*)h3);

  k_loss<<<LOSS_BLOCKS, 256, 0, stream>>>(usr, pos, neg, deg, Gu4, Gi4, h1, h2, h3, bpart);
  k_final<<<1, 64, 0, stream>>>(bpart, out);
}

// Round 2
// 208.785 us; speedup vs baseline: 1.3145x; 1.1626x over previous
//
#include <hip/hip_runtime.h>

#define NUSERS 100000
#define NITEMS 50000
#define NNODES 150000
#define DIM 64
#define E0 600000
#define E2 (2 * E0)
#define BB 8192
#define LW 1e-4f
#define NN16 150016
#define LOSS_BLOCKS 512
#define SPMM_B 2344    // ceil(NNODES*8 / 512)
#define SPMMB_B 384    // 3*BB*8 / 512

// ---- counting-sort CSR build (no device-scope atomics) ----
#define NBUCK 1172      // ceil(NNODES / 128): bucket = node >> 7
#define CHUNK_E 2048    // edges per chunk
#define CHUNKS 293      // ceil(E0 / CHUNK_E)
#define CPAD 320        // padded chunk stride in cnt matrix (bucket-major)
#define BCAP 3072       // LDS staging cap per bucket (max observed ~1.7K)

// ---- bf16 helpers (fp32 <-> packed bf16 pair in a uint) ----
__device__ __forceinline__ float bf_lo(unsigned u) { return __uint_as_float(u << 16); }
__device__ __forceinline__ float bf_hi(unsigned u) { return __uint_as_float(u & 0xffff0000u); }
__device__ __forceinline__ unsigned rne16(float x) {
  unsigned u = __float_as_uint(x);
  return (u + 0x7fffu + ((u >> 16) & 1u)) >> 16;
}
__device__ __forceinline__ unsigned pack2(float lo, float hi) {
  return rne16(lo) | (rne16(hi) << 16);
}

// Pass 1: per-chunk LDS histogram of bucket counts.
// cnt is bucket-major: cnt[b*CPAD + c] so the per-bucket scan is coalesced.
__global__ __launch_bounds__(256) void k_bcount(const int* __restrict__ eu,
                                                const int* __restrict__ ei,
                                                int* __restrict__ cnt) {
  __shared__ int h[NBUCK];
  for (int i = threadIdx.x; i < NBUCK; i += 256) h[i] = 0;
  __syncthreads();
  int c = blockIdx.x;
  int e0 = c * CHUNK_E;
  int e1 = min(e0 + CHUNK_E, E0);
  for (int e = e0 + threadIdx.x; e < e1; e += 256) {
    int u = eu[e];
    int it = NUSERS + ei[e];
    atomicAdd(&h[u >> 7], 1);
    atomicAdd(&h[it >> 7], 1);
  }
  __syncthreads();
  for (int i = threadIdx.x; i < NBUCK; i += 256) cnt[(size_t)i * CPAD + c] = h[i];
}

// Pass 2a: per-bucket exclusive scan over chunks (wave per bucket, in place)
// + bucket totals. Lane loads are coalesced (bucket-major layout).
__global__ __launch_bounds__(256) void k_bscan1(int* __restrict__ cnt,
                                                int* __restrict__ btot) {
  int b = blockIdx.x * 4 + (threadIdx.x >> 6);   // grid = NBUCK/4 blocks
  int lane = threadIdx.x & 63;
  int* row = cnt + (size_t)b * CPAD;
  int carry = 0;
  for (int c0 = 0; c0 < CHUNKS; c0 += 64) {
    int c = c0 + lane;
    int v = (c < CHUNKS) ? row[c] : 0;
    int s = v;
    #pragma unroll
    for (int m = 1; m < 64; m <<= 1) {
      int t = __shfl_up(s, m);
      if (lane >= m) s += t;
    }
    if (c < CHUNKS) row[c] = carry + s - v;      // exclusive within bucket
    carry += __shfl(s, 63);
  }
  if (lane == 63) btot[b] = carry;
}

// Pass 2b: exclusive scan of bucket totals -> bbase (CSR region starts).
__global__ void k_bbase(const int* __restrict__ btot, int* __restrict__ bbase) {
  __shared__ int s[1024];
  int t = threadIdx.x;
  int i0 = 2 * t, i1 = 2 * t + 1;
  int v0 = (i0 < NBUCK) ? btot[i0] : 0;
  int v1 = (i1 < NBUCK) ? btot[i1] : 0;
  s[t] = v0 + v1;
  __syncthreads();
  for (int off = 1; off < 1024; off <<= 1) {
    int x = 0;
    if (t >= off) x = s[t - off];
    __syncthreads();
    if (t >= off) s[t] += x;
    __syncthreads();
  }
  int base = (t > 0) ? s[t - 1] : 0;
  if (i0 < NBUCK) bbase[i0] = base;
  if (i1 < NBUCK) bbase[i1] = base + v0;
}

// Pass 3: scatter directed edges into bucket regions. Each chunk owns a
// disjoint window per bucket (from the matrix scan) -> LDS atomics only.
// Payload: (neighbor_id << 7) | (dst & 127); neighbor < 150016 < 2^18.
__global__ __launch_bounds__(256) void k_bscatter(const int* __restrict__ eu,
                                                  const int* __restrict__ ei,
                                                  const int* __restrict__ cnt,
                                                  const int* __restrict__ bbase,
                                                  unsigned* __restrict__ pk) {
  __shared__ int soff[NBUCK];
  int c = blockIdx.x;
  for (int i = threadIdx.x; i < NBUCK; i += 256)
    soff[i] = cnt[(size_t)i * CPAD + c] + bbase[i];
  __syncthreads();
  int e0 = c * CHUNK_E;
  int e1 = min(e0 + CHUNK_E, E0);
  for (int e = e0 + threadIdx.x; e < e1; e += 256) {
    int u = eu[e];
    int it = NUSERS + ei[e];
    int s1 = atomicAdd(&soff[u >> 7], 1);
    pk[s1] = ((unsigned)it << 7) | (unsigned)(u & 127);
    int s2 = atomicAdd(&soff[it >> 7], 1);
    pk[s2] = ((unsigned)u << 7) | (unsigned)(it & 127);
  }
}

// Pass 4: one block per bucket (128 nodes). LDS histogram -> deg/ptr/dinv,
// LDS rank -> final col. Fused scaled-cast s0 = dinv * G (bf16).
__global__ __launch_bounds__(256) void k_bucket_csr(
    const unsigned* __restrict__ pk, const int* __restrict__ btot,
    const int* __restrict__ bbase, int* __restrict__ deg, int* __restrict__ ptr,
    float* __restrict__ dinv, int* __restrict__ col,
    const float4* __restrict__ Gu4, const float4* __restrict__ Gi4,
    uint2* __restrict__ h0) {
  __shared__ unsigned sitm[BCAP];
  __shared__ int ldeg[128], lscan[128], lcnt[128];
  __shared__ float sdv[128];
  int b = blockIdx.x;
  int base = bbase[b];
  int n = btot[b];
  for (int i = threadIdx.x; i < n; i += 256)
    if (i < BCAP) sitm[i] = pk[base + i];
  if (threadIdx.x < 128) { ldeg[threadIdx.x] = 0; lcnt[threadIdx.x] = 0; }
  __syncthreads();
  for (int i = threadIdx.x; i < n; i += 256) {
    unsigned p = (i < BCAP) ? sitm[i] : pk[base + i];
    atomicAdd(&ldeg[p & 127], 1);
  }
  __syncthreads();
  if (threadIdx.x < 128) lscan[threadIdx.x] = ldeg[threadIdx.x];
  __syncthreads();
  for (int off = 1; off < 128; off <<= 1) {
    int t = 0;
    if (threadIdx.x < 128 && (int)threadIdx.x >= off) t = lscan[threadIdx.x - off];
    __syncthreads();
    if (threadIdx.x < 128 && (int)threadIdx.x >= off) lscan[threadIdx.x] += t;
    __syncthreads();
  }
  int node = b * 128 + threadIdx.x;
  if (threadIdx.x < 128) {
    int d = ldeg[threadIdx.x];
    lscan[threadIdx.x] -= d;               // -> exclusive (bucket-local)
    float dv = d > 0 ? rsqrtf((float)d) : 0.0f;
    sdv[threadIdx.x] = dv;
    if (node < NNODES) {
      deg[node] = d;
      ptr[node] = base + lscan[threadIdx.x];
      dinv[node] = dv;
    }
  }
  __syncthreads();
  for (int i = threadIdx.x; i < n; i += 256) {
    unsigned p = (i < BCAP) ? sitm[i] : pk[base + i];
    int dl = p & 127;
    int pos = base + lscan[dl] + atomicAdd(&lcnt[dl], 1);
    col[pos] = (int)(p >> 7);
  }
  // scaled cast: h0 = bf16(dinv * G) for this bucket's 128 nodes
  for (int w = threadIdx.x; w < 128 * 16; w += 256) {
    int nl = w >> 4, q = w & 15;
    int nd = b * 128 + nl;
    if (nd < NNODES) {
      float dv = sdv[nl];
      float4 v = (nd < NUSERS) ? Gu4[(size_t)nd * 16 + q]
                               : Gi4[(size_t)(nd - NUSERS) * 16 + q];
      h0[(size_t)nd * 16 + q] =
          make_uint2(pack2(dv * v.x, dv * v.y), pack2(dv * v.z, dv * v.w));
    }
  }
}

// Scaled-space SpMM: s_out(n) = dinv(n)^2 * sum_{c in N(n)} s_in(c).
// 8 lanes per node (lane q owns uint4 chunk q of the 128B row); neighbors
// walked sequentially, 2x unrolled (2 gather rows in flight per chain).
// No cross-lane ops, all 64 lanes write (1KB contiguous per wave).
__global__ __launch_bounds__(512) void k_spmm2(
    const int* __restrict__ ptr, const int* __restrict__ deg,
    const int* __restrict__ col, const float* __restrict__ dinv,
    const uint4* __restrict__ h, uint4* __restrict__ hout) {
  int t = blockIdx.x * 512 + threadIdx.x;
  int g = t >> 3;
  int q = t & 7;
  if (g >= NNODES) return;
  int coff;
  const uint4* hsrc;
  if (g < NUSERS) { coff = NUSERS; hsrc = h + (size_t)NUSERS * 8; }
  else { coff = 0; hsrc = h; }
  int st = ptr[g], dg = deg[g];
  float dn = dinv[g];
  float a0 = 0, a1 = 0, a2 = 0, a3 = 0, a4 = 0, a5 = 0, a6 = 0, a7 = 0;
  int jend = st + dg;
  int j = st;
  for (; j + 2 <= jend; j += 2) {
    int c0 = col[j] - coff;
    int c1 = col[j + 1] - coff;
    uint4 x0 = hsrc[(size_t)c0 * 8 + q];
    uint4 x1 = hsrc[(size_t)c1 * 8 + q];
    a0 += bf_lo(x0.x); a1 += bf_hi(x0.x); a2 += bf_lo(x0.y); a3 += bf_hi(x0.y);
    a4 += bf_lo(x0.z); a5 += bf_hi(x0.z); a6 += bf_lo(x0.w); a7 += bf_hi(x0.w);
    a0 += bf_lo(x1.x); a1 += bf_hi(x1.x); a2 += bf_lo(x1.y); a3 += bf_hi(x1.y);
    a4 += bf_lo(x1.z); a5 += bf_hi(x1.z); a6 += bf_lo(x1.w); a7 += bf_hi(x1.w);
  }
  if (j < jend) {
    int c0 = col[j] - coff;
    uint4 x0 = hsrc[(size_t)c0 * 8 + q];
    a0 += bf_lo(x0.x); a1 += bf_hi(x0.x); a2 += bf_lo(x0.y); a3 += bf_hi(x0.y);
    a4 += bf_lo(x0.z); a5 += bf_hi(x0.z); a6 += bf_lo(x0.w); a7 += bf_hi(x0.w);
  }
  float s = dn * dn;
  hout[(size_t)g * 8 + q] = make_uint4(pack2(a0 * s, a1 * s), pack2(a2 * s, a3 * s),
                                       pack2(a4 * s, a5 * s), pack2(a6 * s, a7 * s));
}

__device__ __forceinline__ int decode_node(int k, const int* __restrict__ usr,
                                           const int* __restrict__ pos,
                                           const int* __restrict__ neg, int* coff) {
  if (k < BB) { *coff = NUSERS; return usr[k]; }
  if (k < 2 * BB) { *coff = 0; return NUSERS + pos[k - BB]; }
  *coff = 0; return NUSERS + neg[k - 2 * BB];
}

// Layer-3 SpMM only at the <=3*BB batch nodes (duplicates write identical
// values — benign). Same 8-lanes-per-node structure.
__global__ __launch_bounds__(512) void k_spmm_batch(
    const int* __restrict__ usr, const int* __restrict__ pos, const int* __restrict__ neg,
    const int* __restrict__ ptr, const int* __restrict__ deg,
    const int* __restrict__ col, const float* __restrict__ dinv,
    const uint4* __restrict__ h, uint4* __restrict__ hout) {
  int t = blockIdx.x * 512 + threadIdx.x;
  int k = t >> 3;
  int q = t & 7;
  int coff;
  int g = decode_node(k, usr, pos, neg, &coff);
  const uint4* hsrc = h + (size_t)coff * 8;
  int st = ptr[g], dg = deg[g];
  float dn = dinv[g];
  float a0 = 0, a1 = 0, a2 = 0, a3 = 0, a4 = 0, a5 = 0, a6 = 0, a7 = 0;
  int jend = st + dg;
  int j = st;
  for (; j + 2 <= jend; j += 2) {
    int c0 = col[j] - coff;
    int c1 = col[j + 1] - coff;
    uint4 x0 = hsrc[(size_t)c0 * 8 + q];
    uint4 x1 = hsrc[(size_t)c1 * 8 + q];
    a0 += bf_lo(x0.x); a1 += bf_hi(x0.x); a2 += bf_lo(x0.y); a3 += bf_hi(x0.y);
    a4 += bf_lo(x0.z); a5 += bf_hi(x0.z); a6 += bf_lo(x0.w); a7 += bf_hi(x0.w);
    a0 += bf_lo(x1.x); a1 += bf_hi(x1.x); a2 += bf_lo(x1.y); a3 += bf_hi(x1.y);
    a4 += bf_lo(x1.z); a5 += bf_hi(x1.z); a6 += bf_lo(x1.w); a7 += bf_hi(x1.w);
  }
  if (j < jend) {
    int c0 = col[j] - coff;
    uint4 x0 = hsrc[(size_t)c0 * 8 + q];
    a0 += bf_lo(x0.x); a1 += bf_hi(x0.x); a2 += bf_lo(x0.y); a3 += bf_hi(x0.y);
    a4 += bf_lo(x0.z); a5 += bf_hi(x0.z); a6 += bf_lo(x0.w); a7 += bf_hi(x0.w);
  }
  float s = dn * dn;
  hout[(size_t)g * 8 + q] = make_uint4(pack2(a0 * s, a1 * s), pack2(a2 * s, a3 * s),
                                       pack2(a4 * s, a5 * s), pack2(a6 * s, a7 * s));
}

// Fused batch gather + layer sum + BPR loss; h_l = sqrt(deg)*s_l.
__global__ void k_loss(const int* __restrict__ usr, const int* __restrict__ pos,
                       const int* __restrict__ neg, const int* __restrict__ deg,
                       const float4* __restrict__ Gu4, const float4* __restrict__ Gi4,
                       const uint2* __restrict__ h1, const uint2* __restrict__ h2,
                       const uint2* __restrict__ h3, float* __restrict__ bpart) {
  __shared__ float sL[4], sR[4];
  int wid = threadIdx.x >> 6;
  int lane = threadIdx.x & 63;
  int r = lane >> 4;
  int q = lane & 15;
  int gw = blockIdx.x * 4 + wid;
  int nw = gridDim.x * 4;
  const float s = 0.25f;
  float accL = 0.0f, accR = 0.0f;
  for (int b4 = gw; b4 < BB / 4; b4 += nw) {
    int b = b4 * 4 + r;
    int iu = usr[b], ip = pos[b], ig = neg[b];
    float sdu = sqrtf((float)deg[iu]);
    float sdp = sqrtf((float)deg[NUSERS + ip]);
    float sdn = sqrtf((float)deg[NUSERS + ig]);
    size_t ou = (size_t)iu * 16 + q;
    size_t op = ((size_t)NUSERS + ip) * 16 + q;
    size_t on = ((size_t)NUSERS + ig) * 16 + q;
    float4 u = Gu4[ou];
    float4 p = Gi4[(size_t)ip * 16 + q];
    float4 g = Gi4[(size_t)ig * 16 + q];
    float4 su = {0, 0, 0, 0}, sp = {0, 0, 0, 0}, sg = {0, 0, 0, 0};
    uint2 v;
    v = h1[ou]; su.x += bf_lo(v.x); su.y += bf_hi(v.x); su.z += bf_lo(v.y); su.w += bf_hi(v.y);
    v = h2[ou]; su.x += bf_lo(v.x); su.y += bf_hi(v.x); su.z += bf_lo(v.y); su.w += bf_hi(v.y);
    v = h3[ou]; su.x += bf_lo(v.x); su.y += bf_hi(v.x); su.z += bf_lo(v.y); su.w += bf_hi(v.y);
    v = h1[op]; sp.x += bf_lo(v.x); sp.y += bf_hi(v.x); sp.z += bf_lo(v.y); sp.w += bf_hi(v.y);
    v = h2[op]; sp.x += bf_lo(v.x); sp.y += bf_hi(v.x); sp.z += bf_lo(v.y); sp.w += bf_hi(v.y);
    v = h3[op]; sp.x += bf_lo(v.x); sp.y += bf_hi(v.x); sp.z += bf_lo(v.y); sp.w += bf_hi(v.y);
    v = h1[on]; sg.x += bf_lo(v.x); sg.y += bf_hi(v.x); sg.z += bf_lo(v.y); sg.w += bf_hi(v.y);
    v = h2[on]; sg.x += bf_lo(v.x); sg.y += bf_hi(v.x); sg.z += bf_lo(v.y); sg.w += bf_hi(v.y);
    v = h3[on]; sg.x += bf_lo(v.x); sg.y += bf_hi(v.x); sg.z += bf_lo(v.y); sg.w += bf_hi(v.y);
    u.x = (u.x + sdu * su.x) * s; u.y = (u.y + sdu * su.y) * s;
    u.z = (u.z + sdu * su.z) * s; u.w = (u.w + sdu * su.w) * s;
    p.x = (p.x + sdp * sp.x) * s; p.y = (p.y + sdp * sp.y) * s;
    p.z = (p.z + sdp * sp.z) * s; p.w = (p.w + sdp * sp.w) * s;
    g.x = (g.x + sdn * sg.x) * s; g.y = (g.y + sdn * sg.y) * s;
    g.z = (g.z + sdn * sg.z) * s; g.w = (g.w + sdn * sg.w) * s;
    float dp = u.x * p.x + u.y * p.y + u.z * p.z + u.w * p.w;
    float dn = u.x * g.x + u.y * g.y + u.z * g.z + u.w * g.w;
    float rg = u.x * u.x + u.y * u.y + u.z * u.z + u.w * u.w
             + p.x * p.x + p.y * p.y + p.z * p.z + p.w * p.w
             + g.x * g.x + g.y * g.y + g.z * g.z + g.w * g.w;
    #pragma unroll
    for (int m = 1; m <= 8; m <<= 1) {
      dp += __shfl_xor(dp, m);
      dn += __shfl_xor(dn, m);
      rg += __shfl_xor(rg, m);
    }
    if (q == 0) {
      float diff = dp - dn;
      accL -= fminf(diff, 0.0f) - log1pf(expf(-fabsf(diff)));
      accR += rg;
    }
  }
  accL += __shfl_xor(accL, 16); accR += __shfl_xor(accR, 16);
  accL += __shfl_xor(accL, 32); accR += __shfl_xor(accR, 32);
  if (lane == 0) { sL[wid] = accL; sR[wid] = accR; }
  __syncthreads();
  if (threadIdx.x == 0) {
    bpart[blockIdx.x] = sL[0] + sL[1] + sL[2] + sL[3];
    bpart[LOSS_BLOCKS + blockIdx.x] = sR[0] + sR[1] + sR[2] + sR[3];
  }
}

__global__ void k_final(const float* __restrict__ bpart, float* __restrict__ out) {
  int lane = threadIdx.x;
  float l = 0.0f, r = 0.0f;
  #pragma unroll
  for (int i = 0; i < LOSS_BLOCKS; i += 64) {
    l += bpart[lane + i];
    r += bpart[LOSS_BLOCKS + lane + i];
  }
  for (int off = 32; off > 0; off >>= 1) {
    l += __shfl_down(l, off);
    r += __shfl_down(r, off);
  }
  if (lane == 0) out[0] = l * (1.0f / BB) + LW * 0.5f * r * (1.0f / BB);
}

extern "C" void kernel_launch(void* const* d_in, const int* in_sizes, int n_in,
                              void* d_out, int out_size, void* d_ws, size_t ws_size,
                              hipStream_t stream) {
  const float* Gu = (const float*)d_in[0];
  const float* Gi = (const float*)d_in[1];
  const int* eu  = (const int*)d_in[2];
  const int* ei  = (const int*)d_in[3];
  const int* usr = (const int*)d_in[4];
  const int* pos = (const int*)d_in[5];
  const int* neg = (const int*)d_in[6];
  float* out = (float*)d_out;

  // Workspace: deg/ptr/dinv (1.8 MB) + col (9.6 MB) + h0..h3 (76.8 MB).
  // Build-phase scratch aliases not-yet-live h buffers:
  //   pk (9.6 MB) -> h1, cnt matrix (1.5 MB) -> h2, btot/bbase -> h3.
  int* deg    = (int*)d_ws;                  // NN16
  int* ptr    = deg + NN16;                  // NN16
  float* dinv = (float*)(ptr + NN16);        // NN16
  int* col    = (int*)(dinv + NN16);         // E2
  uint2* h0   = (uint2*)(col + E2);          // NNODES*16 uint2 each (19.2 MB)
  uint2* h1   = h0 + (size_t)NNODES * 16;
  uint2* h2   = h1 + (size_t)NNODES * 16;
  uint2* h3   = h2 + (size_t)NNODES * 16;
  float* bpart = (float*)(h3 + (size_t)NNODES * 16);  // 2*LOSS_BLOCKS

  unsigned* pk = (unsigned*)h1;              // E2 (scattered directed edges)
  int* cnt     = (int*)h2;                   // NBUCK * CPAD
  int* btot    = (int*)h3;                   // NBUCK
  int* bbase   = btot + 1280;                // NBUCK

  const float4* Gu4 = (const float4*)Gu;
  const float4* Gi4 = (const float4*)Gi;

  // CSR build via two-level counting sort — zero device-scope atomics.
  k_bcount<<<CHUNKS, 256, 0, stream>>>(eu, ei, cnt);
  k_bscan1<<<NBUCK / 4, 256, 0, stream>>>(cnt, btot);
  k_bbase<<<1, 1024, 0, stream>>>(btot, bbase);
  k_bscatter<<<CHUNKS, 256, 0, stream>>>(eu, ei, cnt, bbase, pk);
  k_bucket_csr<<<NBUCK, 256, 0, stream>>>(pk, btot, bbase, deg, ptr, dinv, col,
                                          Gu4, Gi4, h0);

  k_spmm2<<<SPMM_B, 512, 0, stream>>>(ptr, deg, col, dinv,
                                      (const uint4*)h0, (uint4*)h1);
  k_spmm2<<<SPMM_B, 512, 0, stream>>>(ptr, deg, col, dinv,
                                      (const uint4*)h1, (uint4*)h2);
  k_spmm_batch<<<SPMMB_B, 512, 0, stream>>>(usr, pos, neg, ptr, deg, col, dinv,
                                            (const uint4*)h2, (uint4*)h3);

  k_loss<<<LOSS_BLOCKS, 256, 0, stream>>>(usr, pos, neg, deg, Gu4, Gi4, h1, h2, h3, bpart);
  k_final<<<1, 64, 0, stream>>>(bpart, out);
}

// Round 4
// 197.068 us; speedup vs baseline: 1.3926x; 1.0595x over previous
//
#include <hip/hip_runtime.h>

#define NUSERS 100000
#define NITEMS 50000
#define NNODES 150000
#define DIM 64
#define E0 600000
#define E2 (2 * E0)
#define BB 8192
#define LW 1e-4f
#define NN16 150016
#define LOSS_BLOCKS 512
#define SPMM_B 2344    // ceil(NNODES*8 / 512)
#define SPMMB_B 384    // 3*BB*8 / 512

// ---- counting-sort CSR build (no device-scope atomics) ----
#define NBUCK 1172      // ceil(NNODES / 128): bucket = node >> 7
#define CHUNK_E 2048    // edges per chunk
#define CHUNKS 293      // ceil(E0 / CHUNK_E)
#define CPAD 320        // padded chunk stride in cnt matrix (bucket-major)
#define BCAP 3072       // LDS staging cap per bucket (max observed ~1.7K)

// ---- bf16 helpers (fp32 <-> packed bf16 pair in a uint) ----
__device__ __forceinline__ float bf_lo(unsigned u) { return __uint_as_float(u << 16); }
__device__ __forceinline__ float bf_hi(unsigned u) { return __uint_as_float(u & 0xffff0000u); }
__device__ __forceinline__ unsigned rne16(float x) {
  unsigned u = __float_as_uint(x);
  return (u + 0x7fffu + ((u >> 16) & 1u)) >> 16;
}
__device__ __forceinline__ unsigned pack2(float lo, float hi) {
  return rne16(lo) | (rne16(hi) << 16);
}

// NOTE: parameter must NOT be named x/y/z/w — macro substitution would
// rewrite the member accesses too (round-3 compile failure).
#define ACC8(X) do { \
    a0 += bf_lo((X).x); a1 += bf_hi((X).x); a2 += bf_lo((X).y); a3 += bf_hi((X).y); \
    a4 += bf_lo((X).z); a5 += bf_hi((X).z); a6 += bf_lo((X).w); a7 += bf_hi((X).w); \
  } while (0)

// Pass 1: per-chunk LDS histogram of bucket counts.
// cnt is bucket-major: cnt[b*CPAD + c] so the per-bucket scan is coalesced.
__global__ __launch_bounds__(256) void k_bcount(const int* __restrict__ eu,
                                                const int* __restrict__ ei,
                                                int* __restrict__ cnt) {
  __shared__ int h[NBUCK];
  for (int i = threadIdx.x; i < NBUCK; i += 256) h[i] = 0;
  __syncthreads();
  int c = blockIdx.x;
  int e0 = c * CHUNK_E;
  int e1 = min(e0 + CHUNK_E, E0);
  for (int e = e0 + threadIdx.x; e < e1; e += 256) {
    int u = eu[e];
    int it = NUSERS + ei[e];
    atomicAdd(&h[u >> 7], 1);
    atomicAdd(&h[it >> 7], 1);
  }
  __syncthreads();
  for (int i = threadIdx.x; i < NBUCK; i += 256) cnt[(size_t)i * CPAD + c] = h[i];
}

// Pass 2a: per-bucket exclusive scan over chunks (wave per bucket, in place)
// + bucket totals. Lane loads are coalesced (bucket-major layout).
__global__ __launch_bounds__(256) void k_bscan1(int* __restrict__ cnt,
                                                int* __restrict__ btot) {
  int b = blockIdx.x * 4 + (threadIdx.x >> 6);   // grid = NBUCK/4 blocks
  int lane = threadIdx.x & 63;
  int* row = cnt + (size_t)b * CPAD;
  int carry = 0;
  for (int c0 = 0; c0 < CHUNKS; c0 += 64) {
    int c = c0 + lane;
    int v = (c < CHUNKS) ? row[c] : 0;
    int s = v;
    #pragma unroll
    for (int m = 1; m < 64; m <<= 1) {
      int t = __shfl_up(s, m);
      if (lane >= m) s += t;
    }
    if (c < CHUNKS) row[c] = carry + s - v;      // exclusive within bucket
    carry += __shfl(s, 63);
  }
  if (lane == 63) btot[b] = carry;
}

// Pass 2b: exclusive scan of bucket totals -> bbase (CSR region starts).
__global__ void k_bbase(const int* __restrict__ btot, int* __restrict__ bbase) {
  __shared__ int s[1024];
  int t = threadIdx.x;
  int i0 = 2 * t, i1 = 2 * t + 1;
  int v0 = (i0 < NBUCK) ? btot[i0] : 0;
  int v1 = (i1 < NBUCK) ? btot[i1] : 0;
  s[t] = v0 + v1;
  __syncthreads();
  for (int off = 1; off < 1024; off <<= 1) {
    int x = 0;
    if (t >= off) x = s[t - off];
    __syncthreads();
    if (t >= off) s[t] += x;
    __syncthreads();
  }
  int base = (t > 0) ? s[t - 1] : 0;
  if (i0 < NBUCK) bbase[i0] = base;
  if (i1 < NBUCK) bbase[i1] = base + v0;
}

// Pass 3: scatter directed edges into bucket regions. Each chunk owns a
// disjoint window per bucket (from the matrix scan) -> LDS atomics only.
// Payload: (neighbor_id << 7) | (dst & 127); neighbor < 150016 < 2^18.
__global__ __launch_bounds__(256) void k_bscatter(const int* __restrict__ eu,
                                                  const int* __restrict__ ei,
                                                  const int* __restrict__ cnt,
                                                  const int* __restrict__ bbase,
                                                  unsigned* __restrict__ pk) {
  __shared__ int soff[NBUCK];
  int c = blockIdx.x;
  for (int i = threadIdx.x; i < NBUCK; i += 256)
    soff[i] = cnt[(size_t)i * CPAD + c] + bbase[i];
  __syncthreads();
  int e0 = c * CHUNK_E;
  int e1 = min(e0 + CHUNK_E, E0);
  for (int e = e0 + threadIdx.x; e < e1; e += 256) {
    int u = eu[e];
    int it = NUSERS + ei[e];
    int s1 = atomicAdd(&soff[u >> 7], 1);
    pk[s1] = ((unsigned)it << 7) | (unsigned)(u & 127);
    int s2 = atomicAdd(&soff[it >> 7], 1);
    pk[s2] = ((unsigned)u << 7) | (unsigned)(it & 127);
  }
}

// Pass 4: one block per bucket (128 nodes). LDS histogram -> deg/ptr/dinv,
// LDS rank into LDS lcol -> coalesced col stream-out (no scattered global
// stores). col stores the neighbor's OPPOSITE-HALF-LOCAL index (dest-half
// decided per item). Fused scaled-cast s0 = dinv * G (bf16).
__global__ __launch_bounds__(256) void k_bucket_csr(
    const unsigned* __restrict__ pk, const int* __restrict__ btot,
    const int* __restrict__ bbase, int* __restrict__ deg, int* __restrict__ ptr,
    float* __restrict__ dinv, int* __restrict__ col,
    const float4* __restrict__ Gu4, const float4* __restrict__ Gi4,
    uint2* __restrict__ h0) {
  __shared__ unsigned sitm[BCAP];
  __shared__ int lcol[BCAP];
  __shared__ int ldeg[128], lscan[128], lcnt[128];
  __shared__ float sdv[128];
  int b = blockIdx.x;
  int base = bbase[b];
  int n = btot[b];
  for (int i = threadIdx.x; i < n; i += 256)
    if (i < BCAP) sitm[i] = pk[base + i];
  if (threadIdx.x < 128) { ldeg[threadIdx.x] = 0; lcnt[threadIdx.x] = 0; }
  __syncthreads();
  for (int i = threadIdx.x; i < n; i += 256) {
    unsigned p = (i < BCAP) ? sitm[i] : pk[base + i];
    atomicAdd(&ldeg[p & 127], 1);
  }
  __syncthreads();
  if (threadIdx.x < 128) lscan[threadIdx.x] = ldeg[threadIdx.x];
  __syncthreads();
  for (int off = 1; off < 128; off <<= 1) {
    int t = 0;
    if (threadIdx.x < 128 && (int)threadIdx.x >= off) t = lscan[threadIdx.x - off];
    __syncthreads();
    if (threadIdx.x < 128 && (int)threadIdx.x >= off) lscan[threadIdx.x] += t;
    __syncthreads();
  }
  int node = b * 128 + threadIdx.x;
  if (threadIdx.x < 128) {
    int d = ldeg[threadIdx.x];
    lscan[threadIdx.x] -= d;               // -> exclusive (bucket-local)
    float dv = d > 0 ? rsqrtf((float)d) : 0.0f;
    sdv[threadIdx.x] = dv;
    if (node < NNODES) {
      deg[node] = d;
      ptr[node] = base + lscan[threadIdx.x];
      dinv[node] = dv;
    }
  }
  __syncthreads();
  for (int i = threadIdx.x; i < n; i += 256) {
    unsigned p = (i < BCAP) ? sitm[i] : pk[base + i];
    int dl = p & 127;
    int nb = (int)(p >> 7);                // neighbor global id
    // dest node id decides which half the neighbor is in -> localize it
    int dnode = b * 128 + dl;
    int val = (dnode < NUSERS) ? nb - NUSERS : nb;
    int rel = lscan[dl] + atomicAdd(&lcnt[dl], 1);
    if (rel < BCAP) lcol[rel] = val;
    else col[base + rel] = val;            // overflow fallback (rare/never)
  }
  __syncthreads();
  int nf = min(n, BCAP);
  for (int i = threadIdx.x; i < nf; i += 256) col[base + i] = lcol[i];
  // scaled cast: h0 = bf16(dinv * G) for this bucket's 128 nodes
  for (int w = threadIdx.x; w < 128 * 16; w += 256) {
    int nl = w >> 4, q = w & 15;
    int nd = b * 128 + nl;
    if (nd < NNODES) {
      float dv = sdv[nl];
      float4 v = (nd < NUSERS) ? Gu4[(size_t)nd * 16 + q]
                               : Gi4[(size_t)(nd - NUSERS) * 16 + q];
      h0[(size_t)nd * 16 + q] =
          make_uint2(pack2(dv * v.x, dv * v.y), pack2(dv * v.z, dv * v.w));
    }
  }
}

// Scaled-space SpMM: s_out(n) = dinv(n)^2 * sum_{c in N(n)} s_in(c).
// 8 lanes per node (lane q owns uint4 chunk q of the 128B row); neighbors
// walked sequentially, 4x unrolled (4 gather rows in flight per chain).
// col holds opposite-half-local ids (no subtract). No cross-lane ops.
__global__ __launch_bounds__(512) void k_spmm2(
    const int* __restrict__ ptr, const int* __restrict__ deg,
    const int* __restrict__ col, const float* __restrict__ dinv,
    const uint4* __restrict__ h, uint4* __restrict__ hout) {
  int t = blockIdx.x * 512 + threadIdx.x;
  int g = t >> 3;
  int q = t & 7;
  if (g >= NNODES) return;
  const uint4* hq = ((g < NUSERS) ? h + (size_t)NUSERS * 8 : h) + q;
  int st = ptr[g], dg = deg[g];
  float dn = dinv[g];
  float a0 = 0, a1 = 0, a2 = 0, a3 = 0, a4 = 0, a5 = 0, a6 = 0, a7 = 0;
  int jend = st + dg;
  int j = st;
  for (; j + 4 <= jend; j += 4) {
    int c0 = col[j], c1 = col[j + 1], c2 = col[j + 2], c3 = col[j + 3];
    uint4 x0 = hq[(size_t)c0 * 8];
    uint4 x1 = hq[(size_t)c1 * 8];
    uint4 x2 = hq[(size_t)c2 * 8];
    uint4 x3 = hq[(size_t)c3 * 8];
    ACC8(x0); ACC8(x1); ACC8(x2); ACC8(x3);
  }
  if (j + 2 <= jend) {
    int c0 = col[j], c1 = col[j + 1];
    uint4 x0 = hq[(size_t)c0 * 8];
    uint4 x1 = hq[(size_t)c1 * 8];
    ACC8(x0); ACC8(x1);
    j += 2;
  }
  if (j < jend) {
    int c0 = col[j];
    uint4 x0 = hq[(size_t)c0 * 8];
    ACC8(x0);
  }
  float s = dn * dn;
  hout[(size_t)g * 8 + q] = make_uint4(pack2(a0 * s, a1 * s), pack2(a2 * s, a3 * s),
                                       pack2(a4 * s, a5 * s), pack2(a6 * s, a7 * s));
}

__device__ __forceinline__ int decode_node(int k, const int* __restrict__ usr,
                                           const int* __restrict__ pos,
                                           const int* __restrict__ neg, int* coff) {
  if (k < BB) { *coff = NUSERS; return usr[k]; }
  if (k < 2 * BB) { *coff = 0; return NUSERS + pos[k - BB]; }
  *coff = 0; return NUSERS + neg[k - 2 * BB];
}

// Layer-3 SpMM only at the 3*BB batch slots. Output is SLOT-indexed
// (e3[k], contiguous 3MB) so writes here and reads in k_loss are coalesced.
__global__ __launch_bounds__(512) void k_spmm_batch(
    const int* __restrict__ usr, const int* __restrict__ pos, const int* __restrict__ neg,
    const int* __restrict__ ptr, const int* __restrict__ deg,
    const int* __restrict__ col, const float* __restrict__ dinv,
    const uint4* __restrict__ h, uint4* __restrict__ e3) {
  int t = blockIdx.x * 512 + threadIdx.x;
  int k = t >> 3;
  int q = t & 7;
  int coff;
  int g = decode_node(k, usr, pos, neg, &coff);
  const uint4* hq = h + (size_t)coff * 8 + q;
  int st = ptr[g], dg = deg[g];
  float dn = dinv[g];
  float a0 = 0, a1 = 0, a2 = 0, a3 = 0, a4 = 0, a5 = 0, a6 = 0, a7 = 0;
  int jend = st + dg;
  int j = st;
  for (; j + 4 <= jend; j += 4) {
    int c0 = col[j], c1 = col[j + 1], c2 = col[j + 2], c3 = col[j + 3];
    uint4 x0 = hq[(size_t)c0 * 8];
    uint4 x1 = hq[(size_t)c1 * 8];
    uint4 x2 = hq[(size_t)c2 * 8];
    uint4 x3 = hq[(size_t)c3 * 8];
    ACC8(x0); ACC8(x1); ACC8(x2); ACC8(x3);
  }
  if (j + 2 <= jend) {
    int c0 = col[j], c1 = col[j + 1];
    uint4 x0 = hq[(size_t)c0 * 8];
    uint4 x1 = hq[(size_t)c1 * 8];
    ACC8(x0); ACC8(x1);
    j += 2;
  }
  if (j < jend) {
    int c0 = col[j];
    uint4 x0 = hq[(size_t)c0 * 8];
    ACC8(x0);
  }
  float s = dn * dn;
  e3[(size_t)k * 8 + q] = make_uint4(pack2(a0 * s, a1 * s), pack2(a2 * s, a3 * s),
                                     pack2(a4 * s, a5 * s), pack2(a6 * s, a7 * s));
}

// Fused batch gather + layer sum + BPR loss; h_l = sqrt(deg)*s_l.
// Layer-3 comes from slot-indexed e3 (coalesced).
__global__ void k_loss(const int* __restrict__ usr, const int* __restrict__ pos,
                       const int* __restrict__ neg, const int* __restrict__ deg,
                       const float4* __restrict__ Gu4, const float4* __restrict__ Gi4,
                       const uint2* __restrict__ h1, const uint2* __restrict__ h2,
                       const uint2* __restrict__ e3, float* __restrict__ bpart) {
  __shared__ float sL[4], sR[4];
  int wid = threadIdx.x >> 6;
  int lane = threadIdx.x & 63;
  int r = lane >> 4;
  int q = lane & 15;
  int gw = blockIdx.x * 4 + wid;
  int nw = gridDim.x * 4;
  const float s = 0.25f;
  float accL = 0.0f, accR = 0.0f;
  for (int b4 = gw; b4 < BB / 4; b4 += nw) {
    int b = b4 * 4 + r;
    int iu = usr[b], ip = pos[b], ig = neg[b];
    float sdu = sqrtf((float)deg[iu]);
    float sdp = sqrtf((float)deg[NUSERS + ip]);
    float sdn = sqrtf((float)deg[NUSERS + ig]);
    size_t ou = (size_t)iu * 16 + q;
    size_t op = ((size_t)NUSERS + ip) * 16 + q;
    size_t on = ((size_t)NUSERS + ig) * 16 + q;
    float4 u = Gu4[ou];
    float4 p = Gi4[(size_t)ip * 16 + q];
    float4 g = Gi4[(size_t)ig * 16 + q];
    float4 su = {0, 0, 0, 0}, sp = {0, 0, 0, 0}, sg = {0, 0, 0, 0};
    uint2 v;
    v = h1[ou]; su.x += bf_lo(v.x); su.y += bf_hi(v.x); su.z += bf_lo(v.y); su.w += bf_hi(v.y);
    v = h2[ou]; su.x += bf_lo(v.x); su.y += bf_hi(v.x); su.z += bf_lo(v.y); su.w += bf_hi(v.y);
    v = e3[(size_t)b * 16 + q];
    su.x += bf_lo(v.x); su.y += bf_hi(v.x); su.z += bf_lo(v.y); su.w += bf_hi(v.y);
    v = h1[op]; sp.x += bf_lo(v.x); sp.y += bf_hi(v.x); sp.z += bf_lo(v.y); sp.w += bf_hi(v.y);
    v = h2[op]; sp.x += bf_lo(v.x); sp.y += bf_hi(v.x); sp.z += bf_lo(v.y); sp.w += bf_hi(v.y);
    v = e3[((size_t)BB + b) * 16 + q];
    sp.x += bf_lo(v.x); sp.y += bf_hi(v.x); sp.z += bf_lo(v.y); sp.w += bf_hi(v.y);
    v = h1[on]; sg.x += bf_lo(v.x); sg.y += bf_hi(v.x); sg.z += bf_lo(v.y); sg.w += bf_hi(v.y);
    v = h2[on]; sg.x += bf_lo(v.x); sg.y += bf_hi(v.x); sg.z += bf_lo(v.y); sg.w += bf_hi(v.y);
    v = e3[((size_t)2 * BB + b) * 16 + q];
    sg.x += bf_lo(v.x); sg.y += bf_hi(v.x); sg.z += bf_lo(v.y); sg.w += bf_hi(v.y);
    u.x = (u.x + sdu * su.x) * s; u.y = (u.y + sdu * su.y) * s;
    u.z = (u.z + sdu * su.z) * s; u.w = (u.w + sdu * su.w) * s;
    p.x = (p.x + sdp * sp.x) * s; p.y = (p.y + sdp * sp.y) * s;
    p.z = (p.z + sdp * sp.z) * s; p.w = (p.w + sdp * sp.w) * s;
    g.x = (g.x + sdn * sg.x) * s; g.y = (g.y + sdn * sg.y) * s;
    g.z = (g.z + sdn * sg.z) * s; g.w = (g.w + sdn * sg.w) * s;
    float dp = u.x * p.x + u.y * p.y + u.z * p.z + u.w * p.w;
    float dn = u.x * g.x + u.y * g.y + u.z * g.z + u.w * g.w;
    float rg = u.x * u.x + u.y * u.y + u.z * u.z + u.w * u.w
             + p.x * p.x + p.y * p.y + p.z * p.z + p.w * p.w
             + g.x * g.x + g.y * g.y + g.z * g.z + g.w * g.w;
    #pragma unroll
    for (int m = 1; m <= 8; m <<= 1) {
      dp += __shfl_xor(dp, m);
      dn += __shfl_xor(dn, m);
      rg += __shfl_xor(rg, m);
    }
    if (q == 0) {
      float diff = dp - dn;
      accL -= fminf(diff, 0.0f) - log1pf(expf(-fabsf(diff)));
      accR += rg;
    }
  }
  accL += __shfl_xor(accL, 16); accR += __shfl_xor(accR, 16);
  accL += __shfl_xor(accL, 32); accR += __shfl_xor(accR, 32);
  if (lane == 0) { sL[wid] = accL; sR[wid] = accR; }
  __syncthreads();
  if (threadIdx.x == 0) {
    bpart[blockIdx.x] = sL[0] + sL[1] + sL[2] + sL[3];
    bpart[LOSS_BLOCKS + blockIdx.x] = sR[0] + sR[1] + sR[2] + sR[3];
  }
}

__global__ void k_final(const float* __restrict__ bpart, float* __restrict__ out) {
  int lane = threadIdx.x;
  float l = 0.0f, r = 0.0f;
  #pragma unroll
  for (int i = 0; i < LOSS_BLOCKS; i += 64) {
    l += bpart[lane + i];
    r += bpart[LOSS_BLOCKS + lane + i];
  }
  for (int off = 32; off > 0; off >>= 1) {
    l += __shfl_down(l, off);
    r += __shfl_down(r, off);
  }
  if (lane == 0) out[0] = l * (1.0f / BB) + LW * 0.5f * r * (1.0f / BB);
}

extern "C" void kernel_launch(void* const* d_in, const int* in_sizes, int n_in,
                              void* d_out, int out_size, void* d_ws, size_t ws_size,
                              hipStream_t stream) {
  const float* Gu = (const float*)d_in[0];
  const float* Gi = (const float*)d_in[1];
  const int* eu  = (const int*)d_in[2];
  const int* ei  = (const int*)d_in[3];
  const int* usr = (const int*)d_in[4];
  const int* pos = (const int*)d_in[5];
  const int* neg = (const int*)d_in[6];
  float* out = (float*)d_out;

  // Workspace: deg/ptr/dinv (1.8 MB) + col (9.6 MB) + h0..h3 (76.8 MB).
  // Build-phase scratch aliases not-yet-live h buffers:
  //   pk (9.6 MB) -> h1, cnt matrix (1.5 MB) -> h2, btot/bbase -> h3.
  //   e3 (slot-indexed layer-3, 3 MB) also lives in h3 (btot/bbase dead
  //   after k_bucket_csr; e3 written by k_spmm_batch afterwards).
  int* deg    = (int*)d_ws;                  // NN16
  int* ptr    = deg + NN16;                  // NN16
  float* dinv = (float*)(ptr + NN16);        // NN16
  int* col    = (int*)(dinv + NN16);         // E2
  uint2* h0   = (uint2*)(col + E2);          // NNODES*16 uint2 each (19.2 MB)
  uint2* h1   = h0 + (size_t)NNODES * 16;
  uint2* h2   = h1 + (size_t)NNODES * 16;
  uint2* h3   = h2 + (size_t)NNODES * 16;
  float* bpart = (float*)(h3 + (size_t)NNODES * 16);  // 2*LOSS_BLOCKS

  unsigned* pk = (unsigned*)h1;              // E2 (scattered directed edges)
  int* cnt     = (int*)h2;                   // NBUCK * CPAD
  int* btot    = (int*)h3;                   // NBUCK
  int* bbase   = btot + 1280;                // NBUCK

  const float4* Gu4 = (const float4*)Gu;
  const float4* Gi4 = (const float4*)Gi;

  // CSR build via two-level counting sort — zero device-scope atomics.
  k_bcount<<<CHUNKS, 256, 0, stream>>>(eu, ei, cnt);
  k_bscan1<<<NBUCK / 4, 256, 0, stream>>>(cnt, btot);
  k_bbase<<<1, 1024, 0, stream>>>(btot, bbase);
  k_bscatter<<<CHUNKS, 256, 0, stream>>>(eu, ei, cnt, bbase, pk);
  k_bucket_csr<<<NBUCK, 256, 0, stream>>>(pk, btot, bbase, deg, ptr, dinv, col,
                                          Gu4, Gi4, h0);

  k_spmm2<<<SPMM_B, 512, 0, stream>>>(ptr, deg, col, dinv,
                                      (const uint4*)h0, (uint4*)h1);
  k_spmm2<<<SPMM_B, 512, 0, stream>>>(ptr, deg, col, dinv,
                                      (const uint4*)h1, (uint4*)h2);
  k_spmm_batch<<<SPMMB_B, 512, 0, stream>>>(usr, pos, neg, ptr, deg, col, dinv,
                                            (const uint4*)h2, (uint4*)h3);

  k_loss<<<LOSS_BLOCKS, 256, 0, stream>>>(usr, pos, neg, deg, Gu4, Gi4, h1, h2,
                                          (const uint2*)h3, bpart);
  k_final<<<1, 64, 0, stream>>>(bpart, out);
}